// Round 3
// baseline (123.298 us; speedup 1.0000x reference)
//
#include <hip/hip_runtime.h>

#define KP    96      // K=85 padded to 96 = 12 octets
#define NF    16
#define NCOL  117     // 16 + 85 + 16 output columns
#define PBLK  (KP * NF)   // 1536 floats per partial block

// ---------------------------------------------------------------------------
// Kernel 1: barrier-free partial QF accumulation.
// 192 threads = ko(12 k-octets) x fh(2 f-halves) x js(8 points/batch).
// Each thread: acc[8k][8f] in registers; per 8-point batch it computes its
// own 8 exp values (2x redundant across fh) and FMAs its F half-row.
// No LDS / no barriers in the main loop. One tree-reduce at the end.
// QX packed as float4{qx,qy,qz,invw2}, TRANSPOSED [kk][ko] so a wave's 12
// distinct addresses spread across 8 bank-quads (<=2-way, free).
// Pad k in [85,96): qx=1e4, invw2=-1 -> exp(-3e8)=0.
// ---------------------------------------------------------------------------
__global__ __launch_bounds__(192) void k1_partial(
    const float* __restrict__ X, const float* __restrict__ F,
    const float* __restrict__ QX, const float* __restrict__ omegaD,
    int K, int nbatch, float* __restrict__ partial)
{
    __shared__ __align__(16) float4 qxc_t[8 * 12];   // [kk][ko]
    __shared__ __align__(16) float rscr[96][64];     // 24 KB reduce scratch

    const int tid = threadIdx.x;
    if (tid < KP) {
        const int k = tid;
        float4 v = make_float4(1.0e4f, 1.0e4f, 1.0e4f, -1.0f);  // pad -> e=0
        if (k < K) {
            v.x = QX[k * 3 + 0];
            v.y = QX[k * 3 + 1];
            v.z = QX[k * 3 + 2];
            const float w = omegaD[k];
            v.w = 1.0f / (w * w);
        }
        qxc_t[(k & 7) * 12 + (k >> 3)] = v;
    }
    __syncthreads();

    const int ko = tid % 12;
    const int fh = (tid / 12) & 1;
    const int js = tid / 24;

    float acc[8][8];
#pragma unroll
    for (int a2 = 0; a2 < 8; ++a2)
#pragma unroll
        for (int b2 = 0; b2 < 8; ++b2) acc[a2][b2] = 0.f;

    for (int b = blockIdx.x; b < nbatch; b += gridDim.x) {
        const int p = b * 8 + js;
        const float x0 = X[p * 3 + 0];
        const float x1 = X[p * 3 + 1];
        const float x2 = X[p * 3 + 2];
        const float4 fa = *reinterpret_cast<const float4*>(&F[(size_t)p * NF + 8 * fh]);
        const float4 fb = *reinterpret_cast<const float4*>(&F[(size_t)p * NF + 8 * fh + 4]);
        const float fv[8] = {fa.x, fa.y, fa.z, fa.w, fb.x, fb.y, fb.z, fb.w};
#pragma unroll
        for (int kk = 0; kk < 8; ++kk) {
            const float4 q = qxc_t[kk * 12 + ko];
            const float dx = x0 - q.x;
            const float dy = x1 - q.y;
            const float dz = x2 - q.z;
            const float e = __expf((dx * dx + dy * dy + dz * dz) * q.w);
#pragma unroll
            for (int u = 0; u < 8; ++u) acc[kk][u] += e * fv[u];
        }
    }

    // ---- reduce over js: 8 -> 4 -> 2 -> 1 ----
#define RSTORE(SLOT)                                                            \
    do {                                                                        \
        float* rp = rscr[SLOT];                                                 \
        _Pragma("unroll")                                                       \
        for (int a2 = 0; a2 < 8; ++a2) {                                        \
            *reinterpret_cast<float4*>(&rp[a2 * 8]) =                           \
                make_float4(acc[a2][0], acc[a2][1], acc[a2][2], acc[a2][3]);    \
            *reinterpret_cast<float4*>(&rp[a2 * 8 + 4]) =                       \
                make_float4(acc[a2][4], acc[a2][5], acc[a2][6], acc[a2][7]);    \
        }                                                                       \
    } while (0)
#define RADD(SLOT)                                                              \
    do {                                                                        \
        const float* rp = rscr[SLOT];                                           \
        _Pragma("unroll")                                                       \
        for (int a2 = 0; a2 < 8; ++a2) {                                        \
            const float4 r0 = *reinterpret_cast<const float4*>(&rp[a2 * 8]);    \
            const float4 r1 = *reinterpret_cast<const float4*>(&rp[a2 * 8 + 4]);\
            acc[a2][0] += r0.x; acc[a2][1] += r0.y;                             \
            acc[a2][2] += r0.z; acc[a2][3] += r0.w;                             \
            acc[a2][4] += r1.x; acc[a2][5] += r1.y;                             \
            acc[a2][6] += r1.z; acc[a2][7] += r1.w;                             \
        }                                                                       \
    } while (0)

    if (tid >= 96 && tid < 192) RSTORE(tid - 96);
    __syncthreads();
    if (tid < 96) RADD(tid);
    __syncthreads();
    if (tid >= 48 && tid < 96) RSTORE(tid - 48);
    __syncthreads();
    if (tid < 48) RADD(tid);
    __syncthreads();
    if (tid >= 24 && tid < 48) RSTORE(tid - 24);
    __syncthreads();
    if (tid < 24) {
        RADD(tid);
        float* pb = partial + (size_t)blockIdx.x * PBLK;
#pragma unroll
        for (int a2 = 0; a2 < 8; ++a2) {
            const int k = ko * 8 + a2;
            *reinterpret_cast<float4*>(&pb[k * NF + 8 * fh]) =
                make_float4(acc[a2][0], acc[a2][1], acc[a2][2], acc[a2][3]);
            *reinterpret_cast<float4*>(&pb[k * NF + 8 * fh + 4]) =
                make_float4(acc[a2][4], acc[a2][5], acc[a2][6], acc[a2][7]);
        }
    }
}

// ---------------------------------------------------------------------------
// Kernel 1.5: fixed-order reduction of partials -> QF (applies omegaF).
// ---------------------------------------------------------------------------
__global__ __launch_bounds__(256) void k1_reduce(
    const float* __restrict__ partial, const float* __restrict__ omegaF,
    int nb, float* __restrict__ QF)
{
    const int k   = blockIdx.x;
    const int tid = threadIdx.x;
    const int f = tid & 15, g = tid >> 4;
    float s = 0.f;
    for (int b = g; b < nb; b += 16)
        s += partial[(size_t)b * PBLK + k * NF + f];
    __shared__ float red[16][17];
    red[g][f] = s;
    __syncthreads();
    if (tid < 16) {
        float t = 0.f;
#pragma unroll
        for (int g2 = 0; g2 < 16; ++g2) t += red[g2][tid];
        QF[k * NF + tid] = t * omegaF[tid];
    }
}

// ---------------------------------------------------------------------------
// Kernel 2: per-point rows [F | FxQFT | FxQFT@QF], LDS-staged + coalesced
// float4 flush. (UNCHANGED from round 2 for clean attribution.)
// ---------------------------------------------------------------------------
__global__ __launch_bounds__(256) void k2_out(
    const float* __restrict__ F, const float* __restrict__ QFb,
    float* __restrict__ out)
{
    __shared__ __align__(16) float QF_lds[85 * 20];
    __shared__ __align__(16) float row[64 * NCOL];   // 29,952 B

    const int tid = threadIdx.x;
    for (int idx = tid; idx < 85 * 16; idx += 256) {
        const int k = idx >> 4, f2 = idx & 15;
        QF_lds[k * 20 + f2] = QFb[idx];
    }
    __syncthreads();

    const int q  = tid & 7;    // k-lane
    const int pp = tid >> 3;   // point-pair 0..31
    const int cbase = blockIdx.x * 256;

    for (int sb = 0; sb < 4; ++sb) {
        const int base = cbase + sb * 64;
        const int i0 = base + pp;
        const int i1 = i0 + 32;

        float fr0[NF], fr1[NF];
        {
            const float4* Fv0 = reinterpret_cast<const float4*>(F + (size_t)i0 * NF);
            const float4* Fv1 = reinterpret_cast<const float4*>(F + (size_t)i1 * NF);
#pragma unroll
            for (int u = 0; u < 4; ++u) {
                const float4 t0 = Fv0[u], t1 = Fv1[u];
                fr0[4 * u + 0] = t0.x; fr0[4 * u + 1] = t0.y;
                fr0[4 * u + 2] = t0.z; fr0[4 * u + 3] = t0.w;
                fr1[4 * u + 0] = t1.x; fr1[4 * u + 1] = t1.y;
                fr1[4 * u + 2] = t1.z; fr1[4 * u + 3] = t1.w;
            }
        }
        row[pp * NCOL + 2 * q]            = fr0[2 * q];
        row[pp * NCOL + 2 * q + 1]        = fr0[2 * q + 1];
        row[(pp + 32) * NCOL + 2 * q]     = fr1[2 * q];
        row[(pp + 32) * NCOL + 2 * q + 1] = fr1[2 * q + 1];

        float g0[NF], g1[NF];
#pragma unroll
        for (int u = 0; u < NF; ++u) { g0[u] = 0.f; g1[u] = 0.f; }

        for (int k = q; k < 85; k += 8) {
            const float* qp = &QF_lds[k * 20];
            const float4 q0 = *reinterpret_cast<const float4*>(qp);
            const float4 q1 = *reinterpret_cast<const float4*>(qp + 4);
            const float4 q2 = *reinterpret_cast<const float4*>(qp + 8);
            const float4 q3 = *reinterpret_cast<const float4*>(qp + 12);
            float qr[NF];
            qr[0]  = q0.x; qr[1]  = q0.y; qr[2]  = q0.z; qr[3]  = q0.w;
            qr[4]  = q1.x; qr[5]  = q1.y; qr[6]  = q1.z; qr[7]  = q1.w;
            qr[8]  = q2.x; qr[9]  = q2.y; qr[10] = q2.z; qr[11] = q2.w;
            qr[12] = q3.x; qr[13] = q3.y; qr[14] = q3.z; qr[15] = q3.w;

            float t0 = 0.f, t1 = 0.f;
#pragma unroll
            for (int u = 0; u < NF; ++u) { t0 += fr0[u] * qr[u]; t1 += fr1[u] * qr[u]; }
            row[pp * NCOL + 16 + k]        = t0;
            row[(pp + 32) * NCOL + 16 + k] = t1;
#pragma unroll
            for (int u = 0; u < NF; ++u) { g0[u] += t0 * qr[u]; g1[u] += t1 * qr[u]; }
        }

#pragma unroll
        for (int m = 1; m <= 4; m <<= 1) {
#pragma unroll
            for (int u = 0; u < NF; ++u) {
                g0[u] += __shfl_xor(g0[u], m);
                g1[u] += __shfl_xor(g1[u], m);
            }
        }
        row[pp * NCOL + 101 + 2 * q]            = g0[2 * q];
        row[pp * NCOL + 101 + 2 * q + 1]        = g0[2 * q + 1];
        row[(pp + 32) * NCOL + 101 + 2 * q]     = g1[2 * q];
        row[(pp + 32) * NCOL + 101 + 2 * q + 1] = g1[2 * q + 1];

        __syncthreads();
        {
            float4* dst = reinterpret_cast<float4*>(out + (size_t)base * NCOL);
            const float4* src = reinterpret_cast<const float4*>(row);
            for (int t = tid; t < (64 * NCOL) / 4; t += 256) dst[t] = src[t];
        }
        __syncthreads();
    }
}

// ---------------------------------------------------------------------------
extern "C" void kernel_launch(void* const* d_in, const int* in_sizes, int n_in,
                              void* d_out, int out_size, void* d_ws, size_t ws_size,
                              hipStream_t stream)
{
    const float* X      = (const float*)d_in[0];
    const float* F      = (const float*)d_in[1];
    const float* QX     = (const float*)d_in[2];
    const float* omegaD = (const float*)d_in[3];
    const float* omegaF = (const float*)d_in[4];
    float* out = (float*)d_out;

    const int M = in_sizes[0] / 3;       // 262144
    const int K = in_sizes[3];           // 85
    const int nbatch = M / 8;            // 32768

    int nb = (int)((ws_size / sizeof(float) - PBLK) / PBLK);
    if (nb > 1280) nb = 1280;            // 5 blocks/CU
    if (nb > nbatch) nb = nbatch;
    if (nb < 1) nb = 1;

    float* partial = (float*)d_ws;
    float* QFbuf   = partial + (size_t)nb * PBLK;

    hipLaunchKernelGGL(k1_partial, dim3(nb), dim3(192), 0, stream,
                       X, F, QX, omegaD, K, nbatch, partial);
    hipLaunchKernelGGL(k1_reduce, dim3(KP), dim3(256), 0, stream,
                       partial, omegaF, nb, QFbuf);
    hipLaunchKernelGGL(k2_out, dim3(M / 256), dim3(256), 0, stream,
                       F, QFbuf, out);
}

// Round 4
// 117.714 us; speedup vs baseline: 1.0474x; 1.0474x over previous
//
#include <hip/hip_runtime.h>

#define KP    96      // K=85 padded to 96 = 12 octets
#define NF    16
#define NCOL  117     // 16 + 85 + 16 output columns
#define PBLK  (KP * NF)   // 1536 floats per partial block

// ---------------------------------------------------------------------------
// Kernel 1: barrier-free partial QF accumulation, q in REGISTERS.
// 192 threads = ko(12 k-octets) x fh(2 f-halves) x js(8 points/batch).
// Each thread owns acc[8k][8f] and qreg[8] = {qx,qy,qz,invw2} (loop-invariant,
// loaded from global once). Main loop: prefetch next batch's X/F, compute
// 8 exp + 64 FMA per point. No LDS, no barriers in the loop.
// Pad k in [85,96): qx=1e4, invw2=-1 -> exp(-3e8)=0.
// ---------------------------------------------------------------------------
__global__ __launch_bounds__(192) void k1_partial(
    const float* __restrict__ X, const float* __restrict__ F,
    const float* __restrict__ QX, const float* __restrict__ omegaD,
    int K, int nbatch, float* __restrict__ partial)
{
    __shared__ __align__(16) float rscr[96][64];     // 24 KB reduce scratch

    const int tid = threadIdx.x;
    const int ko = tid % 12;
    const int fh = (tid / 12) & 1;
    const int js = tid / 24;

    // loop-invariant kernel-structure constants -> registers
    float4 qreg[8];
#pragma unroll
    for (int kk = 0; kk < 8; ++kk) {
        const int k = ko * 8 + kk;
        float4 v = make_float4(1.0e4f, 1.0e4f, 1.0e4f, -1.0f);  // pad -> e=0
        if (k < K) {
            v.x = QX[k * 3 + 0];
            v.y = QX[k * 3 + 1];
            v.z = QX[k * 3 + 2];
            const float w = omegaD[k];
            v.w = 1.0f / (w * w);
        }
        qreg[kk] = v;
    }

    float acc[8][8];
#pragma unroll
    for (int a2 = 0; a2 < 8; ++a2)
#pragma unroll
        for (int b2 = 0; b2 < 8; ++b2) acc[a2][b2] = 0.f;

    // software-pipelined grid-stride loop
    int b = blockIdx.x;
    float x0 = 0.f, x1 = 0.f, x2 = 0.f;
    float4 fa = make_float4(0.f, 0.f, 0.f, 0.f), fb = fa;
    if (b < nbatch) {
        const int p = b * 8 + js;
        x0 = X[p * 3 + 0]; x1 = X[p * 3 + 1]; x2 = X[p * 3 + 2];
        fa = *reinterpret_cast<const float4*>(&F[(size_t)p * NF + 8 * fh]);
        fb = *reinterpret_cast<const float4*>(&F[(size_t)p * NF + 8 * fh + 4]);
    }
    while (b < nbatch) {
        const int bn = b + gridDim.x;
        float nx0 = 0.f, nx1 = 0.f, nx2 = 0.f;
        float4 nfa = make_float4(0.f, 0.f, 0.f, 0.f), nfb = nfa;
        if (bn < nbatch) {
            const int p = bn * 8 + js;
            nx0 = X[p * 3 + 0]; nx1 = X[p * 3 + 1]; nx2 = X[p * 3 + 2];
            nfa = *reinterpret_cast<const float4*>(&F[(size_t)p * NF + 8 * fh]);
            nfb = *reinterpret_cast<const float4*>(&F[(size_t)p * NF + 8 * fh + 4]);
        }

        const float fv[8] = {fa.x, fa.y, fa.z, fa.w, fb.x, fb.y, fb.z, fb.w};
#pragma unroll
        for (int kk = 0; kk < 8; ++kk) {
            const float4 q = qreg[kk];
            const float dx = x0 - q.x;
            const float dy = x1 - q.y;
            const float dz = x2 - q.z;
            const float e = __expf((dx * dx + dy * dy + dz * dz) * q.w);
#pragma unroll
            for (int u = 0; u < 8; ++u) acc[kk][u] += e * fv[u];
        }

        x0 = nx0; x1 = nx1; x2 = nx2; fa = nfa; fb = nfb;
        b = bn;
    }

    // ---- reduce over js: 8 -> 4 -> 2 -> 1 ----
#define RSTORE(SLOT)                                                            \
    do {                                                                        \
        float* rp = rscr[SLOT];                                                 \
        _Pragma("unroll")                                                       \
        for (int a2 = 0; a2 < 8; ++a2) {                                        \
            *reinterpret_cast<float4*>(&rp[a2 * 8]) =                           \
                make_float4(acc[a2][0], acc[a2][1], acc[a2][2], acc[a2][3]);    \
            *reinterpret_cast<float4*>(&rp[a2 * 8 + 4]) =                       \
                make_float4(acc[a2][4], acc[a2][5], acc[a2][6], acc[a2][7]);    \
        }                                                                       \
    } while (0)
#define RADD(SLOT)                                                              \
    do {                                                                        \
        const float* rp = rscr[SLOT];                                           \
        _Pragma("unroll")                                                       \
        for (int a2 = 0; a2 < 8; ++a2) {                                        \
            const float4 r0 = *reinterpret_cast<const float4*>(&rp[a2 * 8]);    \
            const float4 r1 = *reinterpret_cast<const float4*>(&rp[a2 * 8 + 4]);\
            acc[a2][0] += r0.x; acc[a2][1] += r0.y;                             \
            acc[a2][2] += r0.z; acc[a2][3] += r0.w;                             \
            acc[a2][4] += r1.x; acc[a2][5] += r1.y;                             \
            acc[a2][6] += r1.z; acc[a2][7] += r1.w;                             \
        }                                                                       \
    } while (0)

    if (tid >= 96 && tid < 192) RSTORE(tid - 96);
    __syncthreads();
    if (tid < 96) RADD(tid);
    __syncthreads();
    if (tid >= 48 && tid < 96) RSTORE(tid - 48);
    __syncthreads();
    if (tid < 48) RADD(tid);
    __syncthreads();
    if (tid >= 24 && tid < 48) RSTORE(tid - 24);
    __syncthreads();
    if (tid < 24) {
        RADD(tid);
        float* pb = partial + (size_t)blockIdx.x * PBLK;
#pragma unroll
        for (int a2 = 0; a2 < 8; ++a2) {
            const int k = ko * 8 + a2;
            *reinterpret_cast<float4*>(&pb[k * NF + 8 * fh]) =
                make_float4(acc[a2][0], acc[a2][1], acc[a2][2], acc[a2][3]);
            *reinterpret_cast<float4*>(&pb[k * NF + 8 * fh + 4]) =
                make_float4(acc[a2][4], acc[a2][5], acc[a2][6], acc[a2][7]);
        }
    }
}

// ---------------------------------------------------------------------------
// Kernel 1.5: fixed-order reduction of partials -> QF (applies omegaF).
// ---------------------------------------------------------------------------
__global__ __launch_bounds__(256) void k1_reduce(
    const float* __restrict__ partial, const float* __restrict__ omegaF,
    int nb, float* __restrict__ QF)
{
    const int k   = blockIdx.x;
    const int tid = threadIdx.x;
    const int f = tid & 15, g = tid >> 4;
    float s = 0.f;
    for (int b = g; b < nb; b += 16)
        s += partial[(size_t)b * PBLK + k * NF + f];
    __shared__ float red[16][17];
    red[g][f] = s;
    __syncthreads();
    if (tid < 16) {
        float t = 0.f;
#pragma unroll
        for (int g2 = 0; g2 < 16; ++g2) t += red[g2][tid];
        QF[k * NF + tid] = t * omegaF[tid];
    }
}

// ---------------------------------------------------------------------------
// Kernel 2: per-point rows [F | FxQFT | FxQFT@QF], LDS-staged + coalesced
// float4 flush. (UNCHANGED for attribution.)
// ---------------------------------------------------------------------------
__global__ __launch_bounds__(256) void k2_out(
    const float* __restrict__ F, const float* __restrict__ QFb,
    float* __restrict__ out)
{
    __shared__ __align__(16) float QF_lds[85 * 20];
    __shared__ __align__(16) float row[64 * NCOL];   // 29,952 B

    const int tid = threadIdx.x;
    for (int idx = tid; idx < 85 * 16; idx += 256) {
        const int k = idx >> 4, f2 = idx & 15;
        QF_lds[k * 20 + f2] = QFb[idx];
    }
    __syncthreads();

    const int q  = tid & 7;    // k-lane
    const int pp = tid >> 3;   // point-pair 0..31
    const int cbase = blockIdx.x * 256;

    for (int sb = 0; sb < 4; ++sb) {
        const int base = cbase + sb * 64;
        const int i0 = base + pp;
        const int i1 = i0 + 32;

        float fr0[NF], fr1[NF];
        {
            const float4* Fv0 = reinterpret_cast<const float4*>(F + (size_t)i0 * NF);
            const float4* Fv1 = reinterpret_cast<const float4*>(F + (size_t)i1 * NF);
#pragma unroll
            for (int u = 0; u < 4; ++u) {
                const float4 t0 = Fv0[u], t1 = Fv1[u];
                fr0[4 * u + 0] = t0.x; fr0[4 * u + 1] = t0.y;
                fr0[4 * u + 2] = t0.z; fr0[4 * u + 3] = t0.w;
                fr1[4 * u + 0] = t1.x; fr1[4 * u + 1] = t1.y;
                fr1[4 * u + 2] = t1.z; fr1[4 * u + 3] = t1.w;
            }
        }
        row[pp * NCOL + 2 * q]            = fr0[2 * q];
        row[pp * NCOL + 2 * q + 1]        = fr0[2 * q + 1];
        row[(pp + 32) * NCOL + 2 * q]     = fr1[2 * q];
        row[(pp + 32) * NCOL + 2 * q + 1] = fr1[2 * q + 1];

        float g0[NF], g1[NF];
#pragma unroll
        for (int u = 0; u < NF; ++u) { g0[u] = 0.f; g1[u] = 0.f; }

        for (int k = q; k < 85; k += 8) {
            const float* qp = &QF_lds[k * 20];
            const float4 q0 = *reinterpret_cast<const float4*>(qp);
            const float4 q1 = *reinterpret_cast<const float4*>(qp + 4);
            const float4 q2 = *reinterpret_cast<const float4*>(qp + 8);
            const float4 q3 = *reinterpret_cast<const float4*>(qp + 12);
            float qr[NF];
            qr[0]  = q0.x; qr[1]  = q0.y; qr[2]  = q0.z; qr[3]  = q0.w;
            qr[4]  = q1.x; qr[5]  = q1.y; qr[6]  = q1.z; qr[7]  = q1.w;
            qr[8]  = q2.x; qr[9]  = q2.y; qr[10] = q2.z; qr[11] = q2.w;
            qr[12] = q3.x; qr[13] = q3.y; qr[14] = q3.z; qr[15] = q3.w;

            float t0 = 0.f, t1 = 0.f;
#pragma unroll
            for (int u = 0; u < NF; ++u) { t0 += fr0[u] * qr[u]; t1 += fr1[u] * qr[u]; }
            row[pp * NCOL + 16 + k]        = t0;
            row[(pp + 32) * NCOL + 16 + k] = t1;
#pragma unroll
            for (int u = 0; u < NF; ++u) { g0[u] += t0 * qr[u]; g1[u] += t1 * qr[u]; }
        }

#pragma unroll
        for (int m = 1; m <= 4; m <<= 1) {
#pragma unroll
            for (int u = 0; u < NF; ++u) {
                g0[u] += __shfl_xor(g0[u], m);
                g1[u] += __shfl_xor(g1[u], m);
            }
        }
        row[pp * NCOL + 101 + 2 * q]            = g0[2 * q];
        row[pp * NCOL + 101 + 2 * q + 1]        = g0[2 * q + 1];
        row[(pp + 32) * NCOL + 101 + 2 * q]     = g1[2 * q];
        row[(pp + 32) * NCOL + 101 + 2 * q + 1] = g1[2 * q + 1];

        __syncthreads();
        {
            float4* dst = reinterpret_cast<float4*>(out + (size_t)base * NCOL);
            const float4* src = reinterpret_cast<const float4*>(row);
            for (int t = tid; t < (64 * NCOL) / 4; t += 256) dst[t] = src[t];
        }
        __syncthreads();
    }
}

// ---------------------------------------------------------------------------
extern "C" void kernel_launch(void* const* d_in, const int* in_sizes, int n_in,
                              void* d_out, int out_size, void* d_ws, size_t ws_size,
                              hipStream_t stream)
{
    const float* X      = (const float*)d_in[0];
    const float* F      = (const float*)d_in[1];
    const float* QX     = (const float*)d_in[2];
    const float* omegaD = (const float*)d_in[3];
    const float* omegaF = (const float*)d_in[4];
    float* out = (float*)d_out;

    const int M = in_sizes[0] / 3;       // 262144
    const int K = in_sizes[3];           // 85
    const int nbatch = M / 8;            // 32768

    int nb = (int)((ws_size / sizeof(float) - PBLK) / PBLK);
    if (nb > 1280) nb = 1280;            // 5 blocks/CU resident
    if (nb > nbatch) nb = nbatch;
    if (nb < 1) nb = 1;

    float* partial = (float*)d_ws;
    float* QFbuf   = partial + (size_t)nb * PBLK;

    hipLaunchKernelGGL(k1_partial, dim3(nb), dim3(192), 0, stream,
                       X, F, QX, omegaD, K, nbatch, partial);
    hipLaunchKernelGGL(k1_reduce, dim3(KP), dim3(256), 0, stream,
                       partial, omegaF, nb, QFbuf);
    hipLaunchKernelGGL(k2_out, dim3(M / 256), dim3(256), 0, stream,
                       F, QFbuf, out);
}

// Round 5
// 82.507 us; speedup vs baseline: 1.4944x; 1.4267x over previous
//
#include <hip/hip_runtime.h>

#define KP    96      // K=85 padded to 96 = 12 octets
#define NF    16
#define NCOL  117     // 16 + 85 + 16 output columns
#define PBLK  (KP * NF)   // 1536 floats per partial block
#define NPB   32      // points per block-iteration

// ---------------------------------------------------------------------------
// Kernel 1: wave-per-k-octet partial QF accumulation.
// 768 threads = 12 waves. Wave w owns k-octet w (wave-uniform q -> scalar
// regs). Within a wave: lane = 32 points x 2 f-halves. Each thread owns
// acc[8k][8f] (64 VGPR) and processes one point/iter: 8 exp + 64 FMA.
// X/F loads: 32 consecutive points -> fully coalesced, shared by all 12
// waves via L1. 1 block/CU (12 waves = 3/SIMD structural residency).
// Tail: 5-step shfl_xor butterfly over point lanes + 6KB LDS gather.
// Pad k in [85,96): qx=1e4, invw2=-1 -> exp(-3e8)=0.
// ---------------------------------------------------------------------------
__global__ __launch_bounds__(768, 3) void k1_partial(
    const float* __restrict__ X, const float* __restrict__ F,
    const float* __restrict__ QX, const float* __restrict__ omegaD,
    int K, int nchunk, float* __restrict__ partial)
{
    __shared__ __align__(16) float red[12 * 2 * 64];   // 6 KB

    const int tid  = threadIdx.x;
    const int lane = tid & 63;
    const int oct  = __builtin_amdgcn_readfirstlane(tid >> 6);  // wave id 0..11
    const int fh   = lane >> 5;     // f-half
    const int pl   = lane & 31;     // point lane

    // loop-invariant kernel constants (wave-uniform -> scalar-cached)
    float4 qreg[8];
#pragma unroll
    for (int kk = 0; kk < 8; ++kk) {
        const int k = oct * 8 + kk;
        float4 v = make_float4(1.0e4f, 1.0e4f, 1.0e4f, -1.0f);  // pad -> e=0
        if (k < K) {
            v.x = QX[k * 3 + 0];
            v.y = QX[k * 3 + 1];
            v.z = QX[k * 3 + 2];
            const float w = omegaD[k];
            v.w = 1.0f / (w * w);
        }
        qreg[kk] = v;
    }

    float acc[8][8];
#pragma unroll
    for (int a2 = 0; a2 < 8; ++a2)
#pragma unroll
        for (int b2 = 0; b2 < 8; ++b2) acc[a2][b2] = 0.f;

    // software-pipelined grid-stride loop over 32-point chunks
    int pb = blockIdx.x;
    float x0 = 0.f, x1 = 0.f, x2 = 0.f;
    float4 fa = make_float4(0.f, 0.f, 0.f, 0.f), fb = fa;
    if (pb < nchunk) {
        const int p = pb * NPB + pl;
        x0 = X[p * 3 + 0]; x1 = X[p * 3 + 1]; x2 = X[p * 3 + 2];
        fa = *reinterpret_cast<const float4*>(&F[(size_t)p * NF + 8 * fh]);
        fb = *reinterpret_cast<const float4*>(&F[(size_t)p * NF + 8 * fh + 4]);
    }
    while (pb < nchunk) {
        const int pn = pb + gridDim.x;
        float nx0 = 0.f, nx1 = 0.f, nx2 = 0.f;
        float4 nfa = make_float4(0.f, 0.f, 0.f, 0.f), nfb = nfa;
        if (pn < nchunk) {
            const int p = pn * NPB + pl;
            nx0 = X[p * 3 + 0]; nx1 = X[p * 3 + 1]; nx2 = X[p * 3 + 2];
            nfa = *reinterpret_cast<const float4*>(&F[(size_t)p * NF + 8 * fh]);
            nfb = *reinterpret_cast<const float4*>(&F[(size_t)p * NF + 8 * fh + 4]);
        }

        float e[8];
#pragma unroll
        for (int kk = 0; kk < 8; ++kk) {
            const float4 q = qreg[kk];
            const float dx = x0 - q.x;
            const float dy = x1 - q.y;
            const float dz = x2 - q.z;
            e[kk] = __expf((dx * dx + dy * dy + dz * dz) * q.w);
        }
        const float fv[8] = {fa.x, fa.y, fa.z, fa.w, fb.x, fb.y, fb.z, fb.w};
#pragma unroll
        for (int kk = 0; kk < 8; ++kk)
#pragma unroll
            for (int u = 0; u < 8; ++u) acc[kk][u] += e[kk] * fv[u];

        x0 = nx0; x1 = nx1; x2 = nx2; fa = nfa; fb = nfb;
        pb = pn;
    }

    // ---- butterfly reduce over the 32 point lanes (bits 0..4; fh = bit 5) ----
#pragma unroll
    for (int m = 1; m <= 16; m <<= 1) {
#pragma unroll
        for (int a2 = 0; a2 < 8; ++a2)
#pragma unroll
            for (int b2 = 0; b2 < 8; ++b2)
                acc[a2][b2] += __shfl_xor(acc[a2][b2], m);
    }
    if (pl == 0) {
        float* rp = &red[oct * 128 + fh * 64];
#pragma unroll
        for (int a2 = 0; a2 < 8; ++a2) {
            *reinterpret_cast<float4*>(&rp[a2 * 8]) =
                make_float4(acc[a2][0], acc[a2][1], acc[a2][2], acc[a2][3]);
            *reinterpret_cast<float4*>(&rp[a2 * 8 + 4]) =
                make_float4(acc[a2][4], acc[a2][5], acc[a2][6], acc[a2][7]);
        }
    }
    __syncthreads();
    // red[oct][fh][kk*8+fi] -> partial[blk][(oct*8+kk)*16 + fh*8 + fi]
    float* pbase = partial + (size_t)blockIdx.x * PBLK;
    for (int idx = tid; idx < PBLK; idx += 768) {
        const int o2 = idx >> 7;          // octet
        const int r  = idx & 127;
        const int kk = r >> 4;
        const int f  = r & 15;
        pbase[idx] = red[o2 * 128 + (f >> 3) * 64 + kk * 8 + (f & 7)];
    }
}

// ---------------------------------------------------------------------------
// Kernel 1.5: fixed-order reduction of partials -> QF (applies omegaF).
// ---------------------------------------------------------------------------
__global__ __launch_bounds__(256) void k1_reduce(
    const float* __restrict__ partial, const float* __restrict__ omegaF,
    int nb, float* __restrict__ QF)
{
    const int k   = blockIdx.x;
    const int tid = threadIdx.x;
    const int f = tid & 15, g = tid >> 4;
    float s = 0.f;
    for (int b = g; b < nb; b += 16)
        s += partial[(size_t)b * PBLK + k * NF + f];
    __shared__ float red[16][17];
    red[g][f] = s;
    __syncthreads();
    if (tid < 16) {
        float t = 0.f;
#pragma unroll
        for (int g2 = 0; g2 < 16; ++g2) t += red[g2][tid];
        QF[k * NF + tid] = t * omegaF[tid];
    }
}

// ---------------------------------------------------------------------------
// Kernel 2: per-point rows [F | FxQFT | FxQFT@QF], LDS-staged + coalesced
// float4 flush. (UNCHANGED for attribution.)
// ---------------------------------------------------------------------------
__global__ __launch_bounds__(256) void k2_out(
    const float* __restrict__ F, const float* __restrict__ QFb,
    float* __restrict__ out)
{
    __shared__ __align__(16) float QF_lds[85 * 20];
    __shared__ __align__(16) float row[64 * NCOL];   // 29,952 B

    const int tid = threadIdx.x;
    for (int idx = tid; idx < 85 * 16; idx += 256) {
        const int k = idx >> 4, f2 = idx & 15;
        QF_lds[k * 20 + f2] = QFb[idx];
    }
    __syncthreads();

    const int q  = tid & 7;    // k-lane
    const int pp = tid >> 3;   // point-pair 0..31
    const int cbase = blockIdx.x * 256;

    for (int sb = 0; sb < 4; ++sb) {
        const int base = cbase + sb * 64;
        const int i0 = base + pp;
        const int i1 = i0 + 32;

        float fr0[NF], fr1[NF];
        {
            const float4* Fv0 = reinterpret_cast<const float4*>(F + (size_t)i0 * NF);
            const float4* Fv1 = reinterpret_cast<const float4*>(F + (size_t)i1 * NF);
#pragma unroll
            for (int u = 0; u < 4; ++u) {
                const float4 t0 = Fv0[u], t1 = Fv1[u];
                fr0[4 * u + 0] = t0.x; fr0[4 * u + 1] = t0.y;
                fr0[4 * u + 2] = t0.z; fr0[4 * u + 3] = t0.w;
                fr1[4 * u + 0] = t1.x; fr1[4 * u + 1] = t1.y;
                fr1[4 * u + 2] = t1.z; fr1[4 * u + 3] = t1.w;
            }
        }
        row[pp * NCOL + 2 * q]            = fr0[2 * q];
        row[pp * NCOL + 2 * q + 1]        = fr0[2 * q + 1];
        row[(pp + 32) * NCOL + 2 * q]     = fr1[2 * q];
        row[(pp + 32) * NCOL + 2 * q + 1] = fr1[2 * q + 1];

        float g0[NF], g1[NF];
#pragma unroll
        for (int u = 0; u < NF; ++u) { g0[u] = 0.f; g1[u] = 0.f; }

        for (int k = q; k < 85; k += 8) {
            const float* qp = &QF_lds[k * 20];
            const float4 q0 = *reinterpret_cast<const float4*>(qp);
            const float4 q1 = *reinterpret_cast<const float4*>(qp + 4);
            const float4 q2 = *reinterpret_cast<const float4*>(qp + 8);
            const float4 q3 = *reinterpret_cast<const float4*>(qp + 12);
            float qr[NF];
            qr[0]  = q0.x; qr[1]  = q0.y; qr[2]  = q0.z; qr[3]  = q0.w;
            qr[4]  = q1.x; qr[5]  = q1.y; qr[6]  = q1.z; qr[7]  = q1.w;
            qr[8]  = q2.x; qr[9]  = q2.y; qr[10] = q2.z; qr[11] = q2.w;
            qr[12] = q3.x; qr[13] = q3.y; qr[14] = q3.z; qr[15] = q3.w;

            float t0 = 0.f, t1 = 0.f;
#pragma unroll
            for (int u = 0; u < NF; ++u) { t0 += fr0[u] * qr[u]; t1 += fr1[u] * qr[u]; }
            row[pp * NCOL + 16 + k]        = t0;
            row[(pp + 32) * NCOL + 16 + k] = t1;
#pragma unroll
            for (int u = 0; u < NF; ++u) { g0[u] += t0 * qr[u]; g1[u] += t1 * qr[u]; }
        }

#pragma unroll
        for (int m = 1; m <= 4; m <<= 1) {
#pragma unroll
            for (int u = 0; u < NF; ++u) {
                g0[u] += __shfl_xor(g0[u], m);
                g1[u] += __shfl_xor(g1[u], m);
            }
        }
        row[pp * NCOL + 101 + 2 * q]            = g0[2 * q];
        row[pp * NCOL + 101 + 2 * q + 1]        = g0[2 * q + 1];
        row[(pp + 32) * NCOL + 101 + 2 * q]     = g1[2 * q];
        row[(pp + 32) * NCOL + 101 + 2 * q + 1] = g1[2 * q + 1];

        __syncthreads();
        {
            float4* dst = reinterpret_cast<float4*>(out + (size_t)base * NCOL);
            const float4* src = reinterpret_cast<const float4*>(row);
            for (int t = tid; t < (64 * NCOL) / 4; t += 256) dst[t] = src[t];
        }
        __syncthreads();
    }
}

// ---------------------------------------------------------------------------
extern "C" void kernel_launch(void* const* d_in, const int* in_sizes, int n_in,
                              void* d_out, int out_size, void* d_ws, size_t ws_size,
                              hipStream_t stream)
{
    const float* X      = (const float*)d_in[0];
    const float* F      = (const float*)d_in[1];
    const float* QX     = (const float*)d_in[2];
    const float* omegaD = (const float*)d_in[3];
    const float* omegaF = (const float*)d_in[4];
    float* out = (float*)d_out;

    const int M = in_sizes[0] / 3;       // 262144
    const int K = in_sizes[3];           // 85
    const int nchunk = M / NPB;          // 8192

    int nb = (int)((ws_size / sizeof(float) - PBLK) / PBLK);
    if (nb > 256) nb = 256;              // 1 block/CU (12 waves)
    if (nb > nchunk) nb = nchunk;
    if (nb < 1) nb = 1;

    float* partial = (float*)d_ws;
    float* QFbuf   = partial + (size_t)nb * PBLK;

    hipLaunchKernelGGL(k1_partial, dim3(nb), dim3(768), 0, stream,
                       X, F, QX, omegaD, K, nchunk, partial);
    hipLaunchKernelGGL(k1_reduce, dim3(KP), dim3(256), 0, stream,
                       partial, omegaF, nb, QFbuf);
    hipLaunchKernelGGL(k2_out, dim3(M / 256), dim3(256), 0, stream,
                       F, QFbuf, out);
}